// Round 10
// baseline (585.726 us; speedup 1.0000x reference)
//
#include <hip/hip_runtime.h>
#include <hip/hip_bf16.h>

// Problem constants
#define N_TOK   576
#define MPAD    640            // padded to 5*128
#define DIM     1024
#define VOCAB   262400
#define BM      128
#define BN      128
#define BK      64             // k-elements per step (fp8: 64 B rows)
#define RB      5              // MPAD/BM row blocks
#define VBLKS   (VOCAB/BN)     // 2050
#define NWG     (RB*VBLKS)     // 10250
#define IGNORE_INDEX (-100)

typedef float f32x4 __attribute__((ext_vector_type(4)));

__device__ __forceinline__ int cvt4_fp8(float4 v) {
  int r = __builtin_amdgcn_cvt_pk_fp8_f32(v.x, v.y, 0, false);   // bytes 0,1
  r     = __builtin_amdgcn_cvt_pk_fp8_f32(v.z, v.w, r, true);    // bytes 2,3
  return r;
}
__device__ __forceinline__ long lo64(uint4 v) {
  union { uint2 u; long l; } c; c.u = make_uint2(v.x, v.y); return c.l;
}
__device__ __forceinline__ long hi64(uint4 v) {
  union { uint2 u; long l; } c; c.u = make_uint2(v.z, v.w); return c.l;
}

// Raw barrier: orders LDS ops only (lgkmcnt). NO vmcnt drain -- global loads
// stay in flight across it and are waited at their consumers by the
// compiler's counted vmcnt. (Safe: no global_load_lds anywhere in k_gemm.)
#define BARRIER() do {                                          \
    asm volatile("s_waitcnt lgkmcnt(0)" ::: "memory");          \
    __builtin_amdgcn_s_barrier();                               \
  } while (0)

// ---------- kernel 1: x fp32 -> fp8 e4m3, rows [576,640) zero-padded ----------
__global__ void k_cvt_x(const float* __restrict__ x, unsigned char* __restrict__ xq) {
  int idx = blockIdx.x * 256 + threadIdx.x;
  long e0 = (long)idx * 8;
  int row = (int)(e0 >> 10);
  uint2 o;
  if (row < N_TOK) {
    float4 a = *(const float4*)(x + e0);
    float4 b = *(const float4*)(x + e0 + 4);
    o.x = (unsigned)cvt4_fp8(a);
    o.y = (unsigned)cvt4_fp8(b);
  } else { o.x = o.y = 0u; }
  *(uint2*)(xq + e0) = o;
}

// ---------- kernel 2: fp8 GEMM + softcap + exp + row-sum ----------
// vs R9: (1) A frags come DIRECTLY from global (Xq is L1/L2-resident):
// lane (l15,lh) reads 16 contiguous bytes of its token row at k0+lh*16 --
// low 8 B = k-window0 (global 8B-chunks {0,2,4,6}), high 8 B = window1.
// The SAME window split is used for B, so each MFMA contracts a consistent
// 32-k subset and window0+window1 = the full K=64. (2) With global_load_lds
// gone, barriers are raw s_barrier + lgkmcnt(0) only -- NO vmcnt(0) drain,
// so B/A global loads stay in flight across barriers (the R9 stall).
// (3) B frag = one ds_read_b128 (chunk lh) from the paired-row swizzled
// tile (conflict-free: 8 lanes per 128B line cover all 8 slots).
__global__ __launch_bounds__(256, 3) void k_gemm(
    const float* __restrict__ W,            // [VOCAB][DIM] fp32
    const unsigned char* __restrict__ Xq,   // [MPAD][DIM] fp8
    float* __restrict__ S)                  // [MPAD] running sum of exp(z-30)
{
  __shared__ unsigned char Bsl[BN * BK];    // 8 KB (64 pair-lines x 128 B)

  // ---- bijective XCD swizzle (m204), rb-fastest logical order ----
  const int q  = NWG / 8, rm = NWG % 8;     // 1281, 2
  const int orig = blockIdx.x;
  const int xcd  = orig & 7;
  const int part = orig >> 3;
  const int bid  = (xcd < rm ? xcd * (q + 1) : rm * (q + 1) + (xcd - rm) * q) + part;

  const int rb  = bid % RB;
  const int vb  = bid / RB;
  const int m0  = rb * BM;
  const long n0 = (long)vb * BN;

  const int t   = threadIdx.x;
  const int l   = t & 63;
  const int w   = t >> 6;
  const int wm  = w >> 1, wn = w & 1;       // 2x2 waves, 64x64 per wave
  const int l15 = l & 15, lh = l >> 4;

  // ---- A-direct: 4 row pointers (mi), 16B at k0 + lh*16 each step ----
  const unsigned char* asrc[4];
  #pragma unroll
  for (int mi = 0; mi < 4; ++mi)
    asrc[mi] = Xq + (size_t)(m0 + wm * 64 + mi * 16 + l15) * DIM + lh * 16;

  // ---- B staging (R9-identical): 8-float groups -> swizzled 8B slots ----
  const float* bsrc[4];
  int boff[4];
  #pragma unroll
  for (int i = 0; i < 4; ++i) {
    int lin = t + i * 256;                  // 0..1023
    int r   = lin >> 3;                     // row 0..127
    int g   = lin & 7;                      // 8-float group (8 fp8 bytes)
    bsrc[i] = W + (n0 + r) * DIM + g * 8;
    int p = r >> 1, s = r & 1;
    int jj = g >> 1, hb = g & 1;            // 16B chunk, 8B half
    boff[i] = p * 128 + ((((s << 2) | jj) ^ (p & 7)) << 4) + (hb << 3);
  }
  // ---- B frag read: one b128 per ni at global chunk lh of the row ----
  int bro[4];
  #pragma unroll
  for (int ni = 0; ni < 4; ++ni) {
    int row = wn * 64 + ni * 16 + l15;
    int p   = row >> 1;                     // p&7 == l15>>1
    bro[ni] = p * 128 + (((((row & 1) << 2) | lh) ^ (p & 7)) << 4);
  }

  f32x4 acc[4][4];
  const f32x4 zero4 = {0.0f, 0.0f, 0.0f, 0.0f};
  #pragma unroll
  for (int i = 0; i < 4; ++i)
    #pragma unroll
    for (int j = 0; j < 4; ++j) acc[i][j] = zero4;

  for (int k0 = 0; k0 < DIM; k0 += BK) {
    // -- issue ALL global loads at step top (fly across the raw barriers) --
    float4 fb[4][2];
    #pragma unroll
    for (int i = 0; i < 4; ++i) {
      fb[i][0] = *(const float4*)(bsrc[i] + k0);
      fb[i][1] = *(const float4*)(bsrc[i] + k0 + 4);
    }
    uint4 ua[4];
    #pragma unroll
    for (int mi = 0; mi < 4; ++mi)
      ua[mi] = *(const uint4*)(asrc[mi] + k0);

    BARRIER();                              // prev-iter B frag reads done (lgkm)

    // -- B: cvt fp32->fp8 (vmcnt-waited here, per-wave), swizzled 8B writes --
    #pragma unroll
    for (int i = 0; i < 4; ++i) {
      int lo = cvt4_fp8(fb[i][0]);
      int hi = cvt4_fp8(fb[i][1]);
      *(int2*)(Bsl + boff[i]) = make_int2(lo, hi);
    }
    BARRIER();                              // B tile published (lgkm)

    // -- B frags: 4 x ds_read_b128, conflict-free --
    uint4 ub[4];
    #pragma unroll
    for (int ni = 0; ni < 4; ++ni)
      ub[ni] = *(const uint4*)(Bsl + bro[ni]);

    // -- MFMA: window0 (low 8B) then window1 (high 8B) --
    __builtin_amdgcn_s_setprio(1);
    #pragma unroll
    for (int mi = 0; mi < 4; ++mi)
      #pragma unroll
      for (int ni = 0; ni < 4; ++ni)
        acc[mi][ni] = __builtin_amdgcn_mfma_f32_16x16x32_fp8_fp8(
            lo64(ua[mi]), lo64(ub[ni]), acc[mi][ni], 0, 0, 0);
    #pragma unroll
    for (int mi = 0; mi < 4; ++mi)
      #pragma unroll
      for (int ni = 0; ni < 4; ++ni)
        acc[mi][ni] = __builtin_amdgcn_mfma_f32_16x16x32_fp8_fp8(
            hi64(ua[mi]), hi64(ub[ni]), acc[mi][ni], 0, 0, 0);
    __builtin_amdgcn_s_setprio(0);
  }

  // ---- epilogue: p = exp(z-30) = exp(-60/(exp(g/15)+1)); row sums; atomics
  // C frag layout (shape-determined, HW-validated R7-R9): col=l15, row=lh*4+j
  #pragma unroll
  for (int mi = 0; mi < 4; ++mi) {
    #pragma unroll
    for (int j = 0; j < 4; ++j) {
      float s = 0.0f;
      #pragma unroll
      for (int ni = 0; ni < 4; ++ni) {
        float g   = acc[mi][ni][j];
        float tp1 = __expf(g * (1.0f / 15.0f)) + 1.0f;
        s += __expf(-60.0f * __builtin_amdgcn_rcpf(tp1));
      }
      s += __shfl_xor(s, 1);
      s += __shfl_xor(s, 2);
      s += __shfl_xor(s, 4);
      s += __shfl_xor(s, 8);
      if (l15 == 0) {
        int row = m0 + wm * 64 + mi * 16 + lh * 4 + j;
        atomicAdd(&S[row], s);              // padded rows land in S[576..640)
      }
    }
  }
}

// ---------- kernel 3: exact fp32 target logits ----------
__global__ void k_tgt(const float* __restrict__ x, const float* __restrict__ W,
                      const int* __restrict__ labels, float* __restrict__ tgt) {
  int n = blockIdx.x;
  int lab = labels[n];
  int t = threadIdx.x;
  float s = 0.0f;
  if (lab >= 0) {
    const float4 a = ((const float4*)(x + (size_t)n * DIM))[t];
    const float4 b = ((const float4*)(W + (size_t)lab * DIM))[t];
    s = a.x*b.x + a.y*b.y + a.z*b.z + a.w*b.w;
  }
  #pragma unroll
  for (int off = 32; off >= 1; off >>= 1) s += __shfl_xor(s, off);
  __shared__ float wsum[4];
  if ((t & 63) == 0) wsum[t >> 6] = s;
  __syncthreads();
  if (t == 0) {
    float d = wsum[0] + wsum[1] + wsum[2] + wsum[3];
    tgt[n] = (lab >= 0) ? 30.0f * tanhf(d * (1.0f / 30.0f)) : 0.0f;
  }
}

// ---------- kernel 4: final reduce -> loss ----------
__global__ void k_final(const float* __restrict__ S, const float* __restrict__ tgt,
                        const int* __restrict__ labels, float* __restrict__ out) {
  int t = threadIdx.x;
  float sum = 0.0f, cnt = 0.0f;
  for (int n = t; n < N_TOK; n += 256) {
    if (labels[n] != IGNORE_INDEX) {
      sum += 30.0f + __logf(S[n]) - tgt[n];  // lse = 30 + log(sum exp(z-30))
      cnt += 1.0f;
    }
  }
  #pragma unroll
  for (int off = 32; off >= 1; off >>= 1) {
    sum += __shfl_xor(sum, off);
    cnt += __shfl_xor(cnt, off);
  }
  __shared__ float as_[4], ac_[4];
  if ((t & 63) == 0) { as_[t >> 6] = sum; ac_[t >> 6] = cnt; }
  __syncthreads();
  if (t == 0) out[0] = (as_[0]+as_[1]+as_[2]+as_[3]) / (ac_[0]+ac_[1]+ac_[2]+ac_[3]);
}

extern "C" void kernel_launch(void* const* d_in, const int* in_sizes, int n_in,
                              void* d_out, int out_size, void* d_ws, size_t ws_size,
                              hipStream_t stream) {
  const float* x      = (const float*)d_in[0];
  const float* W      = (const float*)d_in[1];
  const int*   labels = (const int*)d_in[2];
  float* out = (float*)d_out;

  // ws layout: xq [640*1024 fp8] | S [640 f32] | tgt [576 f32]  (~0.66 MB)
  char* ws = (char*)d_ws;
  unsigned char* xq = (unsigned char*)ws;
  float* S   = (float*)(ws + (size_t)MPAD * DIM);
  float* tgt = S + MPAD;

  hipMemsetAsync(S, 0, MPAD * sizeof(float), stream);   // zero accumulators
  k_cvt_x<<<MPAD * DIM / (256 * 8), 256, 0, stream>>>(x, xq);
  k_gemm<<<NWG, 256, 0, stream>>>(W, xq, S);
  k_tgt<<<N_TOK, 256, 0, stream>>>(x, W, labels, tgt);
  k_final<<<1, 256, 0, stream>>>(S, tgt, labels, out);
}

// Round 11
// 497.065 us; speedup vs baseline: 1.1784x; 1.1784x over previous
//
#include <hip/hip_runtime.h>
#include <hip/hip_bf16.h>

// Problem constants
#define N_TOK   576
#define MPAD    640            // padded to 5*128
#define DIM     1024
#define VOCAB   262400
#define BM      128
#define BN      128
#define BK      64             // k-elements per step (fp8: 64 B rows)
#define NT      (DIM/BK)       // 16 K-steps
#define RB      5              // MPAD/BM row blocks
#define VBLKS   (VOCAB/BN)     // 2050
#define NWG     (RB*VBLKS)     // 10250
#define IGNORE_INDEX (-100)

typedef float f32x4 __attribute__((ext_vector_type(4)));

#define AS1 __attribute__((address_space(1)))
#define AS3 __attribute__((address_space(3)))

__device__ __forceinline__ int cvt4_fp8(float4 v) {
  int r = __builtin_amdgcn_cvt_pk_fp8_f32(v.x, v.y, 0, false);   // bytes 0,1
  r     = __builtin_amdgcn_cvt_pk_fp8_f32(v.z, v.w, r, true);    // bytes 2,3
  return r;
}

// ---------- kernel 1: x fp32 -> fp8 e4m3, rows [576,640) zero-padded ----------
__global__ void k_cvt_x(const float* __restrict__ x, unsigned char* __restrict__ xq) {
  int idx = blockIdx.x * 256 + threadIdx.x;
  long e0 = (long)idx * 8;
  int row = (int)(e0 >> 10);
  uint2 o;
  if (row < N_TOK) {
    float4 a = *(const float4*)(x + e0);
    float4 b = *(const float4*)(x + e0 + 4);
    o.x = (unsigned)cvt4_fp8(a);
    o.y = (unsigned)cvt4_fp8(b);
  } else { o.x = o.y = 0u; }
  *(uint2*)(xq + e0) = o;
}

// ---------- kernel 2: fp8 GEMM, R9 geometry + 1-iter prefetch pipeline ----
// R9's paired-row LDS layout (conflict-free) kept verbatim. Changes:
//  (1) B global loads prefetched ONE FULL ITERATION ahead: cvt B(k) first
//      (its loads landed ~1500cyc ago, zero stall), then the same registers
//      are reloaded with B(k+1).
//  (2) A LDS double-buffered (+8KB): A(k+1) gload_lds issues right after
//      barrier1 of iter k, is drained by counted vmcnt(10) at barrier2 of
//      iter k+1 (a full iteration later). Never vmcnt(0) mid-loop.
//  (3) Raw s_barrier + lgkmcnt(0) barriers (no block-wide vm drain);
//      sched_barrier(0) after waitcnt pairs (rule #18).
// Steady iter k: BAR1 -> issue A(k+1) -> cvt+write B(k) -> issue B(k+1)
//   -> lgkm(0), vmcnt(10) [A(k) landed; 10 newer in flight], BAR2
//   -> frag ds_reads (A buf k&1, B) -> 16 MFMA.
__global__ __launch_bounds__(256, 3) void k_gemm(
    const float* __restrict__ W,            // [VOCAB][DIM] fp32
    const unsigned char* __restrict__ Xq,   // [MPAD][DIM] fp8
    float* __restrict__ S)                  // [MPAD] running sum of exp(z-30)
{
  __shared__ unsigned char Asl[2 * BM * BK];  // 16 KB (2 x 64 pair-lines)
  __shared__ unsigned char Bsl[BN * BK];      //  8 KB

  // ---- bijective XCD swizzle (m204), rb-fastest logical order ----
  const int q  = NWG / 8, rm = NWG % 8;     // 1281, 2
  const int orig = blockIdx.x;
  const int xcd  = orig & 7;
  const int part = orig >> 3;
  const int bid  = (xcd < rm ? xcd * (q + 1) : rm * (q + 1) + (xcd - rm) * q) + part;

  const int rb  = bid % RB;
  const int vb  = bid / RB;
  const int m0  = rb * BM;
  const long n0 = (long)vb * BN;

  const int t   = threadIdx.x;
  const int l   = t & 63;
  const int w   = t >> 6;
  const int wm  = w >> 1, wn = w & 1;       // 2x2 waves, 64x64 per wave
  const int l15 = l & 15, lh = l >> 4;

  // ---- A staging: gload_lds linear dest, inverse-swizzled source (R9) ----
  const unsigned char* asrc[2];
  #pragma unroll
  for (int i = 0; i < 2; ++i) {
    int lin = t + i * 256;                  // 0..511
    int p   = lin >> 3;
    int c   = (lin & 7) ^ (p & 7);
    asrc[i] = Xq + (size_t)(m0 + 2 * p + (c >> 2)) * DIM + (c & 3) * 16;
  }
  // ---- B staging (R9): 8-float groups -> swizzled 8B slots ----
  const float* bsrc[4];
  int boff[4];
  #pragma unroll
  for (int i = 0; i < 4; ++i) {
    int lin = t + i * 256;                  // 0..1023
    int r   = lin >> 3;                     // row 0..127
    int g   = lin & 7;
    bsrc[i] = W + (n0 + r) * DIM + g * 8;
    int p = r >> 1, s = r & 1;
    int jj = g >> 1, hb = g & 1;
    boff[i] = p * 128 + ((((s << 2) | jj) ^ (p & 7)) << 4) + (hb << 3);
  }
  // ---- frag read offsets (paired-row swizzle, R9) ----
  const int pr = l15 >> 1, sr = l15 & 1;
  int fo[2];
  #pragma unroll
  for (int kk = 0; kk < 2; ++kk)
    fo[kk] = pr * 128 + (((((sr << 2) | (kk * 2 + (lh >> 1))) ^ pr)) << 4)
           + ((lh & 1) << 3);
  const int abase = wm * 4096;
  const int bbase = wn * 4096;

  f32x4 acc[4][4];
  const f32x4 zero4 = {0.0f, 0.0f, 0.0f, 0.0f};
  #pragma unroll
  for (int i = 0; i < 4; ++i)
    #pragma unroll
    for (int j = 0; j < 4; ++j) acc[i][j] = zero4;

  float4 fb[4][2];                          // B staging regs (reused each iter)

  // ---- prologue: issue A(0) -> Abuf0, then B(0) -> fb ----
  #pragma unroll
  for (int i = 0; i < 2; ++i)
    __builtin_amdgcn_global_load_lds((const AS1 void*)(asrc[i]),
        (AS3 void*)(Asl + (t + i * 256) * 16), 16, 0, 0);
  #pragma unroll
  for (int i = 0; i < 4; ++i) {
    fb[i][0] = *(const float4*)(bsrc[i]);
    fb[i][1] = *(const float4*)(bsrc[i] + 4);
  }

  #pragma unroll
  for (int kt = 0; kt < NT; ++kt) {
    const int rbuf = kt & 1;

    // -- BARRIER1: all waves' prev-iter frag reads complete --
    asm volatile("s_waitcnt lgkmcnt(0)" ::: "memory");
    __builtin_amdgcn_s_barrier();
    __builtin_amdgcn_sched_barrier(0);

    // -- issue A(kt+1) into the other A buffer (drained NEXT iter) --
    if (kt < NT - 1) {
      #pragma unroll
      for (int i = 0; i < 2; ++i)
        __builtin_amdgcn_global_load_lds(
            (const AS1 void*)(asrc[i] + (kt + 1) * BK),
            (AS3 void*)(Asl + (rbuf ^ 1) * 8192 + (t + i * 256) * 16), 16, 0, 0);
    }
    // -- cvt B(kt) (loads landed an iteration ago) -> swizzled ds_write --
    #pragma unroll
    for (int i = 0; i < 4; ++i) {
      int lo = cvt4_fp8(fb[i][0]);
      int hi = cvt4_fp8(fb[i][1]);
      *(int2*)(Bsl + boff[i]) = make_int2(lo, hi);
    }
    // -- issue B(kt+1) into the (now dead) fb registers --
    if (kt < NT - 1) {
      #pragma unroll
      for (int i = 0; i < 4; ++i) {
        fb[i][0] = *(const float4*)(bsrc[i] + (kt + 1) * BK);
        fb[i][1] = *(const float4*)(bsrc[i] + (kt + 1) * BK + 4);
      }
    }
    // -- BARRIER2: B writes visible + A(kt) landed; 10 newer ops in flight --
    asm volatile("s_waitcnt lgkmcnt(0)" ::: "memory");
    if (kt < NT - 1) asm volatile("s_waitcnt vmcnt(10)" ::: "memory");
    else             asm volatile("s_waitcnt vmcnt(0)"  ::: "memory");
    __builtin_amdgcn_sched_barrier(0);
    __builtin_amdgcn_s_barrier();
    __builtin_amdgcn_sched_barrier(0);

    // -- fragments (ds_read_b64, conflict-free) + MFMA --
    long af[4][2], bf[4][2];
    #pragma unroll
    for (int mi = 0; mi < 4; ++mi) {
      af[mi][0] = *(const long*)(Asl + rbuf * 8192 + abase + mi * 1024 + fo[0]);
      af[mi][1] = *(const long*)(Asl + rbuf * 8192 + abase + mi * 1024 + fo[1]);
    }
    #pragma unroll
    for (int ni = 0; ni < 4; ++ni) {
      bf[ni][0] = *(const long*)(Bsl + bbase + ni * 1024 + fo[0]);
      bf[ni][1] = *(const long*)(Bsl + bbase + ni * 1024 + fo[1]);
    }
    __builtin_amdgcn_s_setprio(1);
    #pragma unroll
    for (int kk = 0; kk < 2; ++kk)
      #pragma unroll
      for (int mi = 0; mi < 4; ++mi)
        #pragma unroll
        for (int ni = 0; ni < 4; ++ni)
          acc[mi][ni] = __builtin_amdgcn_mfma_f32_16x16x32_fp8_fp8(
              af[mi][kk], bf[ni][kk], acc[mi][ni], 0, 0, 0);
    __builtin_amdgcn_s_setprio(0);
  }

  // ---- epilogue: p = exp(z-30) = exp(-60/(exp(g/15)+1)); row sums; atomics
  // C frag layout (shape-determined, HW-validated R7-R10): col=l15, row=lh*4+j
  #pragma unroll
  for (int mi = 0; mi < 4; ++mi) {
    #pragma unroll
    for (int j = 0; j < 4; ++j) {
      float s = 0.0f;
      #pragma unroll
      for (int ni = 0; ni < 4; ++ni) {
        float g   = acc[mi][ni][j];
        float tp1 = __expf(g * (1.0f / 15.0f)) + 1.0f;
        s += __expf(-60.0f * __builtin_amdgcn_rcpf(tp1));
      }
      s += __shfl_xor(s, 1);
      s += __shfl_xor(s, 2);
      s += __shfl_xor(s, 4);
      s += __shfl_xor(s, 8);
      if (l15 == 0) {
        int row = m0 + wm * 64 + mi * 16 + lh * 4 + j;
        atomicAdd(&S[row], s);              // padded rows land in S[576..640)
      }
    }
  }
}

// ---------- kernel 3: exact fp32 target logits ----------
__global__ void k_tgt(const float* __restrict__ x, const float* __restrict__ W,
                      const int* __restrict__ labels, float* __restrict__ tgt) {
  int n = blockIdx.x;
  int lab = labels[n];
  int t = threadIdx.x;
  float s = 0.0f;
  if (lab >= 0) {
    const float4 a = ((const float4*)(x + (size_t)n * DIM))[t];
    const float4 b = ((const float4*)(W + (size_t)lab * DIM))[t];
    s = a.x*b.x + a.y*b.y + a.z*b.z + a.w*b.w;
  }
  #pragma unroll
  for (int off = 32; off >= 1; off >>= 1) s += __shfl_xor(s, off);
  __shared__ float wsum[4];
  if ((t & 63) == 0) wsum[t >> 6] = s;
  __syncthreads();
  if (t == 0) {
    float d = wsum[0] + wsum[1] + wsum[2] + wsum[3];
    tgt[n] = (lab >= 0) ? 30.0f * tanhf(d * (1.0f / 30.0f)) : 0.0f;
  }
}

// ---------- kernel 4: final reduce -> loss ----------
__global__ void k_final(const float* __restrict__ S, const float* __restrict__ tgt,
                        const int* __restrict__ labels, float* __restrict__ out) {
  int t = threadIdx.x;
  float sum = 0.0f, cnt = 0.0f;
  for (int n = t; n < N_TOK; n += 256) {
    if (labels[n] != IGNORE_INDEX) {
      sum += 30.0f + __logf(S[n]) - tgt[n];  // lse = 30 + log(sum exp(z-30))
      cnt += 1.0f;
    }
  }
  #pragma unroll
  for (int off = 32; off >= 1; off >>= 1) {
    sum += __shfl_xor(sum, off);
    cnt += __shfl_xor(cnt, off);
  }
  __shared__ float as_[4], ac_[4];
  if ((t & 63) == 0) { as_[t >> 6] = sum; ac_[t >> 6] = cnt; }
  __syncthreads();
  if (t == 0) out[0] = (as_[0]+as_[1]+as_[2]+as_[3]) / (ac_[0]+ac_[1]+ac_[2]+ac_[3]);
}

extern "C" void kernel_launch(void* const* d_in, const int* in_sizes, int n_in,
                              void* d_out, int out_size, void* d_ws, size_t ws_size,
                              hipStream_t stream) {
  const float* x      = (const float*)d_in[0];
  const float* W      = (const float*)d_in[1];
  const int*   labels = (const int*)d_in[2];
  float* out = (float*)d_out;

  // ws layout: xq [640*1024 fp8] | S [640 f32] | tgt [576 f32]  (~0.66 MB)
  char* ws = (char*)d_ws;
  unsigned char* xq = (unsigned char*)ws;
  float* S   = (float*)(ws + (size_t)MPAD * DIM);
  float* tgt = S + MPAD;

  hipMemsetAsync(S, 0, MPAD * sizeof(float), stream);   // zero accumulators
  k_cvt_x<<<MPAD * DIM / (256 * 8), 256, 0, stream>>>(x, xq);
  k_gemm<<<NWG, 256, 0, stream>>>(W, xq, S);
  k_tgt<<<N_TOK, 256, 0, stream>>>(x, W, labels, tgt);
  k_final<<<1, 256, 0, stream>>>(S, tgt, labels, out);
}